// Round 1
// baseline (2671.587 us; speedup 1.0000x reference)
//
#include <hip/hip_runtime.h>
#include <cmath>

#define BB   2
#define SS   1024
#define DIMM 3072
#define NHH  24
#define HDD  128
#define MM   (BB * SS)

// ---------------- GEMM: C = X @ W^T + bias ----------------
// X: (M, K) row-major, W: (N, K) row-major, C: (M, N). M via grid.
__global__ __launch_bounds__(256) void gemm_xt_bias(
    const float* __restrict__ X, const float* __restrict__ W,
    const float* __restrict__ bias, float* __restrict__ C,
    int Kdim, int Ndim)
{
    __shared__ float As[16][132];
    __shared__ float Bs[16][132];
    const int tid = threadIdx.x;
    const int tx = tid & 15, ty = tid >> 4;
    const int bm = blockIdx.x * 128, bn = blockIdx.y * 128;
    const int lr = tid >> 2;          // 0..63
    const int lk = (tid & 3) << 2;    // 0,4,8,12

    float acc[8][8];
#pragma unroll
    for (int r = 0; r < 8; ++r)
#pragma unroll
        for (int c = 0; c < 8; ++c) acc[r][c] = 0.f;

    const float* Xp = X + (size_t)(bm + lr) * Kdim + lk;
    const float* Wp = W + (size_t)(bn + lr) * Kdim + lk;

    for (int k0 = 0; k0 < Kdim; k0 += 16) {
        float4 a0 = *(const float4*)(Xp + k0);
        float4 a1 = *(const float4*)(Xp + (size_t)64 * Kdim + k0);
        float4 b0 = *(const float4*)(Wp + k0);
        float4 b1 = *(const float4*)(Wp + (size_t)64 * Kdim + k0);
        __syncthreads();
        As[lk + 0][lr] = a0.x; As[lk + 1][lr] = a0.y; As[lk + 2][lr] = a0.z; As[lk + 3][lr] = a0.w;
        As[lk + 0][lr + 64] = a1.x; As[lk + 1][lr + 64] = a1.y; As[lk + 2][lr + 64] = a1.z; As[lk + 3][lr + 64] = a1.w;
        Bs[lk + 0][lr] = b0.x; Bs[lk + 1][lr] = b0.y; Bs[lk + 2][lr] = b0.z; Bs[lk + 3][lr] = b0.w;
        Bs[lk + 0][lr + 64] = b1.x; Bs[lk + 1][lr + 64] = b1.y; Bs[lk + 2][lr + 64] = b1.z; Bs[lk + 3][lr + 64] = b1.w;
        __syncthreads();
#pragma unroll
        for (int kk = 0; kk < 16; ++kk) {
            float4 av0 = *(const float4*)&As[kk][ty * 4];
            float4 av1 = *(const float4*)&As[kk][ty * 4 + 64];
            float4 bv0 = *(const float4*)&Bs[kk][tx * 4];
            float4 bv1 = *(const float4*)&Bs[kk][tx * 4 + 64];
            float a[8] = {av0.x, av0.y, av0.z, av0.w, av1.x, av1.y, av1.z, av1.w};
            float b[8] = {bv0.x, bv0.y, bv0.z, bv0.w, bv1.x, bv1.y, bv1.z, bv1.w};
#pragma unroll
            for (int r = 0; r < 8; ++r)
#pragma unroll
                for (int c = 0; c < 8; ++c) acc[r][c] = fmaf(a[r], b[c], acc[r][c]);
        }
    }
#pragma unroll
    for (int r = 0; r < 8; ++r) {
        int row = bm + ty * 4 + (r & 3) + (r >> 2) * 64;
#pragma unroll
        for (int cb = 0; cb < 2; ++cb) {
            int col = bn + tx * 4 + cb * 64;
            float4 o;
            o.x = acc[r][cb * 4 + 0] + bias[col + 0];
            o.y = acc[r][cb * 4 + 1] + bias[col + 1];
            o.z = acc[r][cb * 4 + 2] + bias[col + 2];
            o.w = acc[r][cb * 4 + 3] + bias[col + 3];
            *(float4*)&C[(size_t)row * Ndim + col] = o;
        }
    }
}

// ---------------- RMSNorm (over DIM) + RoPE (per head, interleaved pairs) ----------------
// One block per row; blockIdx.y selects q (gq) or k (gk). In place.
__global__ __launch_bounds__(256) void rmsnorm_rope(
    float* __restrict__ q, float* __restrict__ k,
    const float* __restrict__ gq, const float* __restrict__ gk,
    const float* __restrict__ freqs)
{
    float* t = (blockIdx.y == 0) ? q : k;
    const float* g = (blockIdx.y == 0) ? gq : gk;
    const int row = blockIdx.x;
    const int s = row & (SS - 1);      // row = b*S + s
    const int tid = threadIdx.x;
    float* base = t + (size_t)row * DIMM + tid * 12;

    float v[12];
    *(float4*)&v[0] = *(const float4*)(base);
    *(float4*)&v[4] = *(const float4*)(base + 4);
    *(float4*)&v[8] = *(const float4*)(base + 8);

    float ssq = 0.f;
#pragma unroll
    for (int j = 0; j < 12; ++j) ssq += v[j] * v[j];
#pragma unroll
    for (int off = 32; off > 0; off >>= 1) ssq += __shfl_down(ssq, off, 64);
    __shared__ float red[4];
    if ((tid & 63) == 0) red[tid >> 6] = ssq;
    __syncthreads();
    float tot = red[0] + red[1] + red[2] + red[3];
    float sc = rsqrtf(tot * (1.0f / (float)DIMM) + 1e-6f);

    const float* gp = g + tid * 12;
    float y[12];
#pragma unroll
    for (int j = 0; j < 12; ++j) y[j] = v[j] * sc * gp[j];

#pragma unroll
    for (int p = 0; p < 6; ++p) {
        int idx = tid * 12 + 2 * p;
        int f = (idx & 127) >> 1;      // pair index within head
        float ang = freqs[s * 64 + f];
        float cc = cosf(ang), sn = sinf(ang);
        float e = y[2 * p], o = y[2 * p + 1];
        y[2 * p]     = e * cc - o * sn;
        y[2 * p + 1] = e * sn + o * cc;
    }
    *(float4*)(base)     = *(float4*)&y[0];
    *(float4*)(base + 4) = *(float4*)&y[4];
    *(float4*)(base + 8) = *(float4*)&y[8];
}

// ---------------- Flash attention (fp32, online softmax), O written over Q in-place ----------------
__global__ __launch_bounds__(256) void flash_attn(
    float* __restrict__ Q, const float* __restrict__ K,
    const float* __restrict__ V, const int* __restrict__ seq_lens)
{
    __shared__ float Qt[HDD][68];       // Q transposed: [d][qi]
    __shared__ float KV[HDD * 68];      // Kt[d][j] stride 68, then Vs[j][d] stride 132
    __shared__ float Ssm[64][65];
    __shared__ float mrow[64], lrow[64], frow[64];

    const int tid = threadIdx.x;
    const int tx = tid & 15, ty = tid >> 4;
    const int i0 = blockIdx.x * 64;
    const int h = blockIdx.y;
    const int b = blockIdx.z;
    const int slen = seq_lens[b];
    const float scale = 0.08838834764831845f;   // 1/sqrt(128)
    const int gstride = NHH * HDD;              // 3072

    const float* Qg = Q + ((size_t)(b * SS + i0) * NHH + h) * HDD;
#pragma unroll
    for (int rep = 0; rep < 8; ++rep) {
        int f4 = tid + rep * 256;
        int r = f4 >> 5, c4 = (f4 & 31) << 2;
        float4 qv = *(const float4*)(Qg + (size_t)r * gstride + c4);
        Qt[c4 + 0][r] = qv.x; Qt[c4 + 1][r] = qv.y; Qt[c4 + 2][r] = qv.z; Qt[c4 + 3][r] = qv.w;
    }
    if (tid < 64) { mrow[tid] = -3.0e38f; lrow[tid] = 0.f; }

    float accO[4][8];
#pragma unroll
    for (int r = 0; r < 4; ++r)
#pragma unroll
        for (int c = 0; c < 8; ++c) accO[r][c] = 0.f;

    const int nT = (slen + 63) >> 6;
    for (int t = 0; t < nT; ++t) {
        const int j0 = t * 64;
        __syncthreads();   // prev-iter PV reads of KV done
        const float* Kg = K + ((size_t)(b * SS + j0) * NHH + h) * HDD;
#pragma unroll
        for (int rep = 0; rep < 8; ++rep) {
            int f4 = tid + rep * 256;
            int r = f4 >> 5, c4 = (f4 & 31) << 2;
            float4 kv = *(const float4*)(Kg + (size_t)r * gstride + c4);
            KV[(c4 + 0) * 68 + r] = kv.x; KV[(c4 + 1) * 68 + r] = kv.y;
            KV[(c4 + 2) * 68 + r] = kv.z; KV[(c4 + 3) * 68 + r] = kv.w;
        }
        __syncthreads();

        // scores: thread -> qi = ty*4+r, kj = tx*4+c
        float sc4[4][4];
#pragma unroll
        for (int r = 0; r < 4; ++r)
#pragma unroll
            for (int c = 0; c < 4; ++c) sc4[r][c] = 0.f;
        for (int kk = 0; kk < HDD; ++kk) {
            float4 qa = *(const float4*)&Qt[kk][ty * 4];
            float4 kb = *(const float4*)&KV[kk * 68 + tx * 4];
            float a[4] = {qa.x, qa.y, qa.z, qa.w};
            float bb[4] = {kb.x, kb.y, kb.z, kb.w};
#pragma unroll
            for (int r = 0; r < 4; ++r)
#pragma unroll
                for (int c = 0; c < 4; ++c) sc4[r][c] = fmaf(a[r], bb[c], sc4[r][c]);
        }
#pragma unroll
        for (int r = 0; r < 4; ++r)
#pragma unroll
            for (int c = 0; c < 4; ++c) {
                int j = j0 + tx * 4 + c;
                Ssm[ty * 4 + r][tx * 4 + c] = (j < slen) ? sc4[r][c] * scale : -3.0e38f;
            }
        __syncthreads();

        // online softmax per row (serial baseline; optimize later)
        if (tid < 64) {
            float m_old = mrow[tid];
            float tm = -3.0e38f;
            for (int j = 0; j < 64; ++j) tm = fmaxf(tm, Ssm[tid][j]);
            float m_new = fmaxf(m_old, tm);
            float fct = __expf(m_old - m_new);
            float lsum = 0.f;
            for (int j = 0; j < 64; ++j) {
                float p = __expf(Ssm[tid][j] - m_new);
                Ssm[tid][j] = p;
                lsum += p;
            }
            mrow[tid] = m_new;
            lrow[tid] = lrow[tid] * fct + lsum;
            frow[tid] = fct;
        }
        __syncthreads();

        // load V over K's LDS; rescale O
        const float* Vg = V + ((size_t)(b * SS + j0) * NHH + h) * HDD;
#pragma unroll
        for (int rep = 0; rep < 8; ++rep) {
            int f4 = tid + rep * 256;
            int r = f4 >> 5, c4 = (f4 & 31) << 2;
            float4 vv = *(const float4*)(Vg + (size_t)r * gstride + c4);
            *(float4*)&KV[r * 132 + c4] = vv;
        }
        float fr[4];
#pragma unroll
        for (int r = 0; r < 4; ++r) fr[r] = frow[ty * 4 + r];
#pragma unroll
        for (int r = 0; r < 4; ++r)
#pragma unroll
            for (int c = 0; c < 8; ++c) accO[r][c] *= fr[r];
        __syncthreads();

        // PV: O[qi][d] += p[qi][j] * V[j][d];  d = tx*8 + c
        for (int j = 0; j < 64; ++j) {
            float p0 = Ssm[ty * 4 + 0][j];
            float p1 = Ssm[ty * 4 + 1][j];
            float p2 = Ssm[ty * 4 + 2][j];
            float p3 = Ssm[ty * 4 + 3][j];
            float4 v0 = *(const float4*)&KV[j * 132 + tx * 8];
            float4 v1 = *(const float4*)&KV[j * 132 + tx * 8 + 4];
            float vv[8] = {v0.x, v0.y, v0.z, v0.w, v1.x, v1.y, v1.z, v1.w};
#pragma unroll
            for (int c = 0; c < 8; ++c) {
                accO[0][c] = fmaf(p0, vv[c], accO[0][c]);
                accO[1][c] = fmaf(p1, vv[c], accO[1][c]);
                accO[2][c] = fmaf(p2, vv[c], accO[2][c]);
                accO[3][c] = fmaf(p3, vv[c], accO[3][c]);
            }
        }
    }

    float* Og = Q + ((size_t)(b * SS + i0) * NHH + h) * HDD;
#pragma unroll
    for (int r = 0; r < 4; ++r) {
        int qi = ty * 4 + r;
        float linv = 1.0f / lrow[qi];
        float4 o0, o1;
        o0.x = accO[r][0] * linv; o0.y = accO[r][1] * linv;
        o0.z = accO[r][2] * linv; o0.w = accO[r][3] * linv;
        o1.x = accO[r][4] * linv; o1.y = accO[r][5] * linv;
        o1.z = accO[r][6] * linv; o1.w = accO[r][7] * linv;
        *(float4*)(Og + (size_t)qi * gstride + tx * 8)     = o0;
        *(float4*)(Og + (size_t)qi * gstride + tx * 8 + 4) = o1;
    }
}

extern "C" void kernel_launch(void* const* d_in, const int* in_sizes, int n_in,
                              void* d_out, int out_size, void* d_ws, size_t ws_size,
                              hipStream_t stream)
{
    const float* x     = (const float*)d_in[0];
    const int*   seq   = (const int*)d_in[1];
    // d_in[2] = grid_sizes (unused by reference math)
    const float* freqs = (const float*)d_in[3];
    const float* Wq    = (const float*)d_in[4];
    const float* bq    = (const float*)d_in[5];
    const float* Wk    = (const float*)d_in[6];
    const float* bk    = (const float*)d_in[7];
    const float* Wv    = (const float*)d_in[8];
    const float* bv    = (const float*)d_in[9];
    const float* Wo    = (const float*)d_in[10];
    const float* bo    = (const float*)d_in[11];
    const float* gq    = (const float*)d_in[12];
    const float* gk    = (const float*)d_in[13];

    float* out = (float*)d_out;
    float* ws  = (float*)d_ws;
    const size_t MD = (size_t)MM * DIMM;

    float* q = ws;            // q -> attn output (in-place)
    float* k = ws + MD;
    float* v = out;           // v lives in d_out; final GEMM overwrites it after last use

    dim3 ggrid(MM / 128, DIMM / 128);
    gemm_xt_bias<<<ggrid, 256, 0, stream>>>(x, Wq, bq, q, DIMM, DIMM);
    gemm_xt_bias<<<ggrid, 256, 0, stream>>>(x, Wk, bk, k, DIMM, DIMM);
    gemm_xt_bias<<<ggrid, 256, 0, stream>>>(x, Wv, bv, v, DIMM, DIMM);
    rmsnorm_rope<<<dim3(MM, 2), 256, 0, stream>>>(q, k, gq, gk, freqs);
    flash_attn<<<dim3(SS / 64, NHH, BB), 256, 0, stream>>>(q, k, v, seq);
    gemm_xt_bias<<<ggrid, 256, 0, stream>>>(q, Wo, bo, out, DIMM, DIMM);
}

// Round 2
// 1237.220 us; speedup vs baseline: 2.1593x; 2.1593x over previous
//
#include <hip/hip_runtime.h>
#include <hip/hip_bf16.h>
#include <cmath>

#define BB   2
#define SS   1024
#define DIMM 3072
#define NHH  24
#define HDD  128
#define MM   (BB * SS)

typedef __attribute__((ext_vector_type(8))) short short8v;
typedef __attribute__((ext_vector_type(4))) float floatx4;
typedef __attribute__((ext_vector_type(4))) int intx4;

// ---- fp32 -> (hi,lo) bf16 split helpers (hi = truncate, lo = RN(x - hi)) ----
__device__ __forceinline__ unsigned bfbits_rn(float x) {
    union { __hip_bfloat16 b; unsigned short u; } c;
    c.b = __float2bfloat16(x);
    return (unsigned)c.u;
}
__device__ __forceinline__ void cvt_pair(float f0, float f1, unsigned& hi, unsigned& lo) {
    unsigned u0 = __float_as_uint(f0), u1 = __float_as_uint(f1);
    unsigned h0 = u0 & 0xFFFF0000u, h1 = u1 & 0xFFFF0000u;
    hi = (u0 >> 16) | h1;
    float l0 = f0 - __uint_as_float(h0);
    float l1 = f1 - __uint_as_float(h1);
    lo = bfbits_rn(l0) | (bfbits_rn(l1) << 16);
}
__device__ __forceinline__ void cvt_store8(const float4 a, const float4 b,
                                           unsigned short* Hp, unsigned short* Lp) {
    unsigned h0, l0, h1, l1, h2, l2, h3, l3;
    cvt_pair(a.x, a.y, h0, l0); cvt_pair(a.z, a.w, h1, l1);
    cvt_pair(b.x, b.y, h2, l2); cvt_pair(b.z, b.w, h3, l3);
    intx4 H = {(int)h0, (int)h1, (int)h2, (int)h3};
    intx4 L = {(int)l0, (int)l1, (int)l2, (int)l3};
    *(intx4*)Hp = H;
    *(intx4*)Lp = L;
}

// ---------------- GEMM: C = X @ W^T + bias  (split-bf16 MFMA) ----------------
// X: (2048, 3072) row-major, W: (3072, 3072) row-major, C: (2048, 3072).
__global__ __launch_bounds__(256) void gemm_xt_bias_mfma(
    const float* __restrict__ X, const float* __restrict__ W,
    const float* __restrict__ bias, float* __restrict__ C)
{
    constexpr int K = DIMM, N = DIMM;
    constexpr int NSTEP = K / 32;
    __shared__ unsigned short Ah[128 * 32], Al[128 * 32], Bh[128 * 32], Bl[128 * 32];

    const int tid  = threadIdx.x;
    const int lane = tid & 63;
    const int wave = tid >> 6;
    const int wm = wave >> 1, wn = wave & 1;
    const int lr  = lane & 15;
    const int lkb = (lane >> 4) << 3;      // k elem offset 0/8/16/24

    // bijective XCD swizzle (grid = 384 = 8 * 48)
    const int id  = blockIdx.x;
    const int cpx = (int)gridDim.x >> 3;
    const int swz = (id & 7) * cpx + (id >> 3);
    const int bm = (swz & 15) << 7;        // M/128 = 16
    const int bn = (swz >> 4) << 7;        // N/128 = 24

    // staging coords: u = tid + i*256 -> row u>>2, col8 (u&3)*8
    const int r0 = tid >> 2;
    const int c8 = (tid & 3) << 3;
    const float* ap0 = X + (size_t)(bm + r0) * K + c8;
    const float* ap1 = X + (size_t)(bm + r0 + 64) * K + c8;
    const float* bp0 = W + (size_t)(bn + r0) * K + c8;
    const float* bp1 = W + (size_t)(bn + r0 + 64) * K + c8;

    float4 sa[2][2], sb[2][2];
    auto LOAD = [&](int k0) {
        sa[0][0] = *(const float4*)(ap0 + k0); sa[0][1] = *(const float4*)(ap0 + k0 + 4);
        sa[1][0] = *(const float4*)(ap1 + k0); sa[1][1] = *(const float4*)(ap1 + k0 + 4);
        sb[0][0] = *(const float4*)(bp0 + k0); sb[0][1] = *(const float4*)(bp0 + k0 + 4);
        sb[1][0] = *(const float4*)(bp1 + k0); sb[1][1] = *(const float4*)(bp1 + k0 + 4);
    };
    const int off0 = r0 * 32 + c8, off1 = (r0 + 64) * 32 + c8;
    auto STORE = [&]() {
        cvt_store8(sa[0][0], sa[0][1], Ah + off0, Al + off0);
        cvt_store8(sa[1][0], sa[1][1], Ah + off1, Al + off1);
        cvt_store8(sb[0][0], sb[0][1], Bh + off0, Bl + off0);
        cvt_store8(sb[1][0], sb[1][1], Bh + off1, Bl + off1);
    };

    floatx4 acc[4][4];
#pragma unroll
    for (int i = 0; i < 4; ++i)
#pragma unroll
        for (int j = 0; j < 4; ++j) acc[i][j] = (floatx4){0.f, 0.f, 0.f, 0.f};

    LOAD(0);
    for (int ks = 0; ks < NSTEP; ++ks) {
        __syncthreads();                    // previous compute done reading LDS
        STORE();
        __syncthreads();                    // tiles ready
        if (ks + 1 < NSTEP) LOAD((ks + 1) * 32);  // prefetch flies under MFMA

        short8v ah[4], al[4], bh[4], bl[4];
#pragma unroll
        for (int i = 0; i < 4; ++i) {
            ah[i] = *(const short8v*)(Ah + (wm * 64 + i * 16 + lr) * 32 + lkb);
            al[i] = *(const short8v*)(Al + (wm * 64 + i * 16 + lr) * 32 + lkb);
            bh[i] = *(const short8v*)(Bh + (wn * 64 + i * 16 + lr) * 32 + lkb);
            bl[i] = *(const short8v*)(Bl + (wn * 64 + i * 16 + lr) * 32 + lkb);
        }
#pragma unroll
        for (int mi = 0; mi < 4; ++mi)
#pragma unroll
            for (int ni = 0; ni < 4; ++ni) {
                acc[mi][ni] = __builtin_amdgcn_mfma_f32_16x16x32_bf16(ah[mi], bh[ni], acc[mi][ni], 0, 0, 0);
                acc[mi][ni] = __builtin_amdgcn_mfma_f32_16x16x32_bf16(ah[mi], bl[ni], acc[mi][ni], 0, 0, 0);
                acc[mi][ni] = __builtin_amdgcn_mfma_f32_16x16x32_bf16(al[mi], bh[ni], acc[mi][ni], 0, 0, 0);
            }
    }

    // epilogue: C/D layout col = lane&15, row = (lane>>4)*4 + reg
    const int crow0 = bm + wm * 64 + ((lane >> 4) << 2);
    const int ccol0 = bn + wn * 64;
#pragma unroll
    for (int ni = 0; ni < 4; ++ni) {
        const int col = ccol0 + ni * 16 + lr;
        const float bv = bias[col];
#pragma unroll
        for (int mi = 0; mi < 4; ++mi) {
            const int row = crow0 + mi * 16;
#pragma unroll
            for (int r2 = 0; r2 < 4; ++r2)
                C[(size_t)(row + r2) * N + col] = acc[mi][ni][r2] + bv;
        }
    }
}

// ---------------- RMSNorm (over DIM) + RoPE (per head, interleaved pairs) ----------------
__global__ __launch_bounds__(256) void rmsnorm_rope(
    float* __restrict__ q, float* __restrict__ k,
    const float* __restrict__ gq, const float* __restrict__ gk,
    const float* __restrict__ freqs)
{
    float* t = (blockIdx.y == 0) ? q : k;
    const float* g = (blockIdx.y == 0) ? gq : gk;
    const int row = blockIdx.x;
    const int s = row & (SS - 1);
    const int tid = threadIdx.x;
    float* base = t + (size_t)row * DIMM + tid * 12;

    float v[12];
    *(float4*)&v[0] = *(const float4*)(base);
    *(float4*)&v[4] = *(const float4*)(base + 4);
    *(float4*)&v[8] = *(const float4*)(base + 8);

    float ssq = 0.f;
#pragma unroll
    for (int j = 0; j < 12; ++j) ssq += v[j] * v[j];
#pragma unroll
    for (int off = 32; off > 0; off >>= 1) ssq += __shfl_down(ssq, off, 64);
    __shared__ float red[4];
    if ((tid & 63) == 0) red[tid >> 6] = ssq;
    __syncthreads();
    float tot = red[0] + red[1] + red[2] + red[3];
    float sc = rsqrtf(tot * (1.0f / (float)DIMM) + 1e-6f);

    const float* gp = g + tid * 12;
    float y[12];
#pragma unroll
    for (int j = 0; j < 12; ++j) y[j] = v[j] * sc * gp[j];

#pragma unroll
    for (int p = 0; p < 6; ++p) {
        int idx = tid * 12 + 2 * p;
        int f = (idx & 127) >> 1;
        float ang = freqs[s * 64 + f];
        float cc = cosf(ang), sn = sinf(ang);
        float e = y[2 * p], o = y[2 * p + 1];
        y[2 * p]     = e * cc - o * sn;
        y[2 * p + 1] = e * sn + o * cc;
    }
    *(float4*)(base)     = *(float4*)&y[0];
    *(float4*)(base + 4) = *(float4*)&y[4];
    *(float4*)(base + 8) = *(float4*)&y[8];
}

// ---------------- Flash attention (fp32, online softmax), O written over Q in-place ----------------
__global__ __launch_bounds__(256) void flash_attn(
    float* __restrict__ Q, const float* __restrict__ K,
    const float* __restrict__ V, const int* __restrict__ seq_lens)
{
    __shared__ float Qt[HDD][68];
    __shared__ float KV[HDD * 68];
    __shared__ float Ssm[64][65];
    __shared__ float mrow[64], lrow[64], frow[64];

    const int tid = threadIdx.x;
    const int tx = tid & 15, ty = tid >> 4;
    const int i0 = blockIdx.x * 64;
    const int h = blockIdx.y;
    const int b = blockIdx.z;
    const int slen = seq_lens[b];
    const float scale = 0.08838834764831845f;
    const int gstride = NHH * HDD;

    const float* Qg = Q + ((size_t)(b * SS + i0) * NHH + h) * HDD;
#pragma unroll
    for (int rep = 0; rep < 8; ++rep) {
        int f4 = tid + rep * 256;
        int r = f4 >> 5, c4 = (f4 & 31) << 2;
        float4 qv = *(const float4*)(Qg + (size_t)r * gstride + c4);
        Qt[c4 + 0][r] = qv.x; Qt[c4 + 1][r] = qv.y; Qt[c4 + 2][r] = qv.z; Qt[c4 + 3][r] = qv.w;
    }
    if (tid < 64) { mrow[tid] = -3.0e38f; lrow[tid] = 0.f; }

    float accO[4][8];
#pragma unroll
    for (int r = 0; r < 4; ++r)
#pragma unroll
        for (int c = 0; c < 8; ++c) accO[r][c] = 0.f;

    const int nT = (slen + 63) >> 6;
    for (int t = 0; t < nT; ++t) {
        const int j0 = t * 64;
        __syncthreads();
        const float* Kg = K + ((size_t)(b * SS + j0) * NHH + h) * HDD;
#pragma unroll
        for (int rep = 0; rep < 8; ++rep) {
            int f4 = tid + rep * 256;
            int r = f4 >> 5, c4 = (f4 & 31) << 2;
            float4 kv = *(const float4*)(Kg + (size_t)r * gstride + c4);
            KV[(c4 + 0) * 68 + r] = kv.x; KV[(c4 + 1) * 68 + r] = kv.y;
            KV[(c4 + 2) * 68 + r] = kv.z; KV[(c4 + 3) * 68 + r] = kv.w;
        }
        __syncthreads();

        float sc4[4][4];
#pragma unroll
        for (int r = 0; r < 4; ++r)
#pragma unroll
            for (int c = 0; c < 4; ++c) sc4[r][c] = 0.f;
        for (int kk = 0; kk < HDD; ++kk) {
            float4 qa = *(const float4*)&Qt[kk][ty * 4];
            float4 kb = *(const float4*)&KV[kk * 68 + tx * 4];
            float a[4] = {qa.x, qa.y, qa.z, qa.w};
            float bb2[4] = {kb.x, kb.y, kb.z, kb.w};
#pragma unroll
            for (int r = 0; r < 4; ++r)
#pragma unroll
                for (int c = 0; c < 4; ++c) sc4[r][c] = fmaf(a[r], bb2[c], sc4[r][c]);
        }
#pragma unroll
        for (int r = 0; r < 4; ++r)
#pragma unroll
            for (int c = 0; c < 4; ++c) {
                int j = j0 + tx * 4 + c;
                Ssm[ty * 4 + r][tx * 4 + c] = (j < slen) ? sc4[r][c] * scale : -3.0e38f;
            }
        __syncthreads();

        if (tid < 64) {
            float m_old = mrow[tid];
            float tm = -3.0e38f;
            for (int j = 0; j < 64; ++j) tm = fmaxf(tm, Ssm[tid][j]);
            float m_new = fmaxf(m_old, tm);
            float fct = __expf(m_old - m_new);
            float lsum = 0.f;
            for (int j = 0; j < 64; ++j) {
                float p = __expf(Ssm[tid][j] - m_new);
                Ssm[tid][j] = p;
                lsum += p;
            }
            mrow[tid] = m_new;
            lrow[tid] = lrow[tid] * fct + lsum;
            frow[tid] = fct;
        }
        __syncthreads();

        const float* Vg = V + ((size_t)(b * SS + j0) * NHH + h) * HDD;
#pragma unroll
        for (int rep = 0; rep < 8; ++rep) {
            int f4 = tid + rep * 256;
            int r = f4 >> 5, c4 = (f4 & 31) << 2;
            float4 vv = *(const float4*)(Vg + (size_t)r * gstride + c4);
            *(float4*)&KV[r * 132 + c4] = vv;
        }
        float fr[4];
#pragma unroll
        for (int r = 0; r < 4; ++r) fr[r] = frow[ty * 4 + r];
#pragma unroll
        for (int r = 0; r < 4; ++r)
#pragma unroll
            for (int c = 0; c < 8; ++c) accO[r][c] *= fr[r];
        __syncthreads();

        for (int j = 0; j < 64; ++j) {
            float p0 = Ssm[ty * 4 + 0][j];
            float p1 = Ssm[ty * 4 + 1][j];
            float p2 = Ssm[ty * 4 + 2][j];
            float p3 = Ssm[ty * 4 + 3][j];
            float4 v0 = *(const float4*)&KV[j * 132 + tx * 8];
            float4 v1 = *(const float4*)&KV[j * 132 + tx * 8 + 4];
            float vv[8] = {v0.x, v0.y, v0.z, v0.w, v1.x, v1.y, v1.z, v1.w};
#pragma unroll
            for (int c = 0; c < 8; ++c) {
                accO[0][c] = fmaf(p0, vv[c], accO[0][c]);
                accO[1][c] = fmaf(p1, vv[c], accO[1][c]);
                accO[2][c] = fmaf(p2, vv[c], accO[2][c]);
                accO[3][c] = fmaf(p3, vv[c], accO[3][c]);
            }
        }
    }

    float* Og = Q + ((size_t)(b * SS + i0) * NHH + h) * HDD;
#pragma unroll
    for (int r = 0; r < 4; ++r) {
        int qi = ty * 4 + r;
        float linv = 1.0f / lrow[qi];
        float4 o0, o1;
        o0.x = accO[r][0] * linv; o0.y = accO[r][1] * linv;
        o0.z = accO[r][2] * linv; o0.w = accO[r][3] * linv;
        o1.x = accO[r][4] * linv; o1.y = accO[r][5] * linv;
        o1.z = accO[r][6] * linv; o1.w = accO[r][7] * linv;
        *(float4*)(Og + (size_t)qi * gstride + tx * 8)     = o0;
        *(float4*)(Og + (size_t)qi * gstride + tx * 8 + 4) = o1;
    }
}

extern "C" void kernel_launch(void* const* d_in, const int* in_sizes, int n_in,
                              void* d_out, int out_size, void* d_ws, size_t ws_size,
                              hipStream_t stream)
{
    const float* x     = (const float*)d_in[0];
    const int*   seq   = (const int*)d_in[1];
    const float* freqs = (const float*)d_in[3];
    const float* Wq    = (const float*)d_in[4];
    const float* bq    = (const float*)d_in[5];
    const float* Wk    = (const float*)d_in[6];
    const float* bk    = (const float*)d_in[7];
    const float* Wv    = (const float*)d_in[8];
    const float* bv    = (const float*)d_in[9];
    const float* Wo    = (const float*)d_in[10];
    const float* bo    = (const float*)d_in[11];
    const float* gq    = (const float*)d_in[12];
    const float* gk    = (const float*)d_in[13];

    float* out = (float*)d_out;
    float* ws  = (float*)d_ws;
    const size_t MD = (size_t)MM * DIMM;

    float* q = ws;            // q -> attn output (in-place)
    float* k = ws + MD;
    float* v = out;           // v in d_out; final GEMM overwrites after last use

    const int ngrid = (MM / 128) * (DIMM / 128);   // 384
    gemm_xt_bias_mfma<<<ngrid, 256, 0, stream>>>(x, Wq, bq, q);
    gemm_xt_bias_mfma<<<ngrid, 256, 0, stream>>>(x, Wk, bk, k);
    gemm_xt_bias_mfma<<<ngrid, 256, 0, stream>>>(x, Wv, bv, v);
    rmsnorm_rope<<<dim3(MM, 2), 256, 0, stream>>>(q, k, gq, gk, freqs);
    flash_attn<<<dim3(SS / 64, NHH, BB), 256, 0, stream>>>(q, k, v, seq);
    gemm_xt_bias_mfma<<<ngrid, 256, 0, stream>>>(q, Wo, bo, out);
}

// Round 3
// 894.304 us; speedup vs baseline: 2.9873x; 1.3834x over previous
//
#include <hip/hip_runtime.h>
#include <hip/hip_bf16.h>
#include <cmath>

#define BB   2
#define SS   1024
#define DIMM 3072
#define NHH  24
#define HDD  128
#define MM   (BB * SS)

typedef __attribute__((ext_vector_type(8))) short short8v;
typedef __attribute__((ext_vector_type(4))) short short4v;
typedef __attribute__((ext_vector_type(4))) float floatx4;
typedef __attribute__((ext_vector_type(4))) int intx4;

__device__ __forceinline__ unsigned short bf16u(float x) {
    union { __hip_bfloat16 b; unsigned short u; } c;
    c.b = __float2bfloat16(x);
    return c.u;
}

// ---- fp32 -> (hi,lo) bf16 split helpers (hi = truncate, lo = RN(x - hi)) ----
__device__ __forceinline__ void cvt_pair(float f0, float f1, unsigned& hi, unsigned& lo) {
    unsigned u0 = __float_as_uint(f0), u1 = __float_as_uint(f1);
    unsigned h0 = u0 & 0xFFFF0000u, h1 = u1 & 0xFFFF0000u;
    hi = (u0 >> 16) | h1;
    float l0 = f0 - __uint_as_float(h0);
    float l1 = f1 - __uint_as_float(h1);
    lo = (unsigned)bf16u(l0) | ((unsigned)bf16u(l1) << 16);
}
__device__ __forceinline__ void cvt_store8(const float4 a, const float4 b,
                                           unsigned short* Hp, unsigned short* Lp) {
    unsigned h0, l0, h1, l1, h2, l2, h3, l3;
    cvt_pair(a.x, a.y, h0, l0); cvt_pair(a.z, a.w, h1, l1);
    cvt_pair(b.x, b.y, h2, l2); cvt_pair(b.z, b.w, h3, l3);
    intx4 H = {(int)h0, (int)h1, (int)h2, (int)h3};
    intx4 L = {(int)l0, (int)l1, (int)l2, (int)l3};
    *(intx4*)Hp = H;
    *(intx4*)Lp = L;
}

// ---------------- GEMM: C = X @ W^T + bias  (split-bf16 MFMA) ----------------
__global__ __launch_bounds__(256) void gemm_xt_bias_mfma(
    const float* __restrict__ X, const float* __restrict__ W,
    const float* __restrict__ bias, float* __restrict__ C)
{
    constexpr int K = DIMM, N = DIMM;
    constexpr int NSTEP = K / 32;
    __shared__ unsigned short Ah[128 * 32], Al[128 * 32], Bh[128 * 32], Bl[128 * 32];

    const int tid  = threadIdx.x;
    const int lane = tid & 63;
    const int wave = tid >> 6;
    const int wm = wave >> 1, wn = wave & 1;
    const int lr  = lane & 15;
    const int lkb = (lane >> 4) << 3;

    const int id  = blockIdx.x;
    const int cpx = (int)gridDim.x >> 3;
    const int swz = (id & 7) * cpx + (id >> 3);
    const int bm = (swz & 15) << 7;
    const int bn = (swz >> 4) << 7;

    const int r0 = tid >> 2;
    const int c8 = (tid & 3) << 3;
    const float* ap0 = X + (size_t)(bm + r0) * K + c8;
    const float* ap1 = X + (size_t)(bm + r0 + 64) * K + c8;
    const float* bp0 = W + (size_t)(bn + r0) * K + c8;
    const float* bp1 = W + (size_t)(bn + r0 + 64) * K + c8;

    float4 sa[2][2], sb[2][2];
    auto LOAD = [&](int k0) {
        sa[0][0] = *(const float4*)(ap0 + k0); sa[0][1] = *(const float4*)(ap0 + k0 + 4);
        sa[1][0] = *(const float4*)(ap1 + k0); sa[1][1] = *(const float4*)(ap1 + k0 + 4);
        sb[0][0] = *(const float4*)(bp0 + k0); sb[0][1] = *(const float4*)(bp0 + k0 + 4);
        sb[1][0] = *(const float4*)(bp1 + k0); sb[1][1] = *(const float4*)(bp1 + k0 + 4);
    };
    const int off0 = r0 * 32 + c8, off1 = (r0 + 64) * 32 + c8;
    auto STORE = [&]() {
        cvt_store8(sa[0][0], sa[0][1], Ah + off0, Al + off0);
        cvt_store8(sa[1][0], sa[1][1], Ah + off1, Al + off1);
        cvt_store8(sb[0][0], sb[0][1], Bh + off0, Bl + off0);
        cvt_store8(sb[1][0], sb[1][1], Bh + off1, Bl + off1);
    };

    floatx4 acc[4][4];
#pragma unroll
    for (int i = 0; i < 4; ++i)
#pragma unroll
        for (int j = 0; j < 4; ++j) acc[i][j] = (floatx4){0.f, 0.f, 0.f, 0.f};

    LOAD(0);
    for (int ks = 0; ks < NSTEP; ++ks) {
        __syncthreads();
        STORE();
        __syncthreads();
        if (ks + 1 < NSTEP) LOAD((ks + 1) * 32);

        short8v ah[4], al[4], bh[4], bl[4];
#pragma unroll
        for (int i = 0; i < 4; ++i) {
            ah[i] = *(const short8v*)(Ah + (wm * 64 + i * 16 + lr) * 32 + lkb);
            al[i] = *(const short8v*)(Al + (wm * 64 + i * 16 + lr) * 32 + lkb);
            bh[i] = *(const short8v*)(Bh + (wn * 64 + i * 16 + lr) * 32 + lkb);
            bl[i] = *(const short8v*)(Bl + (wn * 64 + i * 16 + lr) * 32 + lkb);
        }
#pragma unroll
        for (int mi = 0; mi < 4; ++mi)
#pragma unroll
            for (int ni = 0; ni < 4; ++ni) {
                acc[mi][ni] = __builtin_amdgcn_mfma_f32_16x16x32_bf16(ah[mi], bh[ni], acc[mi][ni], 0, 0, 0);
                acc[mi][ni] = __builtin_amdgcn_mfma_f32_16x16x32_bf16(ah[mi], bl[ni], acc[mi][ni], 0, 0, 0);
                acc[mi][ni] = __builtin_amdgcn_mfma_f32_16x16x32_bf16(al[mi], bh[ni], acc[mi][ni], 0, 0, 0);
            }
    }

    const int crow0 = bm + wm * 64 + ((lane >> 4) << 2);
    const int ccol0 = bn + wn * 64;
#pragma unroll
    for (int ni = 0; ni < 4; ++ni) {
        const int col = ccol0 + ni * 16 + lr;
        const float bv = bias[col];
#pragma unroll
        for (int mi = 0; mi < 4; ++mi) {
            const int row = crow0 + mi * 16;
#pragma unroll
            for (int r2 = 0; r2 < 4; ++r2)
                C[(size_t)(row + r2) * N + col] = acc[mi][ni][r2] + bv;
        }
    }
}

// ---------------- RMSNorm + RoPE ----------------
__global__ __launch_bounds__(256) void rmsnorm_rope(
    float* __restrict__ q, float* __restrict__ k,
    const float* __restrict__ gq, const float* __restrict__ gk,
    const float* __restrict__ freqs)
{
    float* t = (blockIdx.y == 0) ? q : k;
    const float* g = (blockIdx.y == 0) ? gq : gk;
    const int row = blockIdx.x;
    const int s = row & (SS - 1);
    const int tid = threadIdx.x;
    float* base = t + (size_t)row * DIMM + tid * 12;

    float v[12];
    *(float4*)&v[0] = *(const float4*)(base);
    *(float4*)&v[4] = *(const float4*)(base + 4);
    *(float4*)&v[8] = *(const float4*)(base + 8);

    float ssq = 0.f;
#pragma unroll
    for (int j = 0; j < 12; ++j) ssq += v[j] * v[j];
#pragma unroll
    for (int off = 32; off > 0; off >>= 1) ssq += __shfl_down(ssq, off, 64);
    __shared__ float red[4];
    if ((tid & 63) == 0) red[tid >> 6] = ssq;
    __syncthreads();
    float tot = red[0] + red[1] + red[2] + red[3];
    float sc = rsqrtf(tot * (1.0f / (float)DIMM) + 1e-6f);

    const float* gp = g + tid * 12;
    float y[12];
#pragma unroll
    for (int j = 0; j < 12; ++j) y[j] = v[j] * sc * gp[j];

#pragma unroll
    for (int p = 0; p < 6; ++p) {
        int idx = tid * 12 + 2 * p;
        int f = (idx & 127) >> 1;
        float ang = freqs[s * 64 + f];
        float cc = cosf(ang), sn = sinf(ang);
        float e = y[2 * p], o = y[2 * p + 1];
        y[2 * p]     = e * cc - o * sn;
        y[2 * p + 1] = e * sn + o * cc;
    }
    *(float4*)(base)     = *(float4*)&y[0];
    *(float4*)(base + 4) = *(float4*)&y[4];
    *(float4*)(base + 8) = *(float4*)&y[8];
}

// ---------------- Flash attention: bf16 MFMA, wave-parallel online softmax ----------------
// Block: 64 q-rows of one (b,h); 4 waves, each owns 16 q-rows. KV tiles of 64.
__global__ __launch_bounds__(256) void flash_attn_mfma(
    float* __restrict__ Q, const float* __restrict__ K,
    const float* __restrict__ V, const int* __restrict__ seq_lens)
{
    // QPs: Q tile [64][128] bf16 (swizzled). After Q-fragment preload, cols 0..63
    // of each wave's 16 rows are reused as that wave's P buffer (per-wave private).
    __shared__ unsigned short QPs[64 * 128];
    __shared__ unsigned short Ks[64 * 128];
    __shared__ unsigned short Vt[128 * 64];   // V transposed [d][j], swizzled

    const int tid  = threadIdx.x;
    const int lane = tid & 63;
    const int wave = tid >> 6;
    const int ln = lane & 15;      // fragment row/col within 16
    const int lq = lane >> 4;      // k-chunk quad
    const int i0 = blockIdx.x * 64;
    const int h  = blockIdx.y;
    const int b  = blockIdx.z;
    const int slen = seq_lens[b];
    const float scale = 0.08838834764831845f;
    const size_t gstride = NHH * HDD;          // 3072

    const float* Qg = Q + ((size_t)(b * SS + i0) * NHH + h) * HDD;

    // ---- stage Q tile (fp32 -> bf16, swizzled) ----
#pragma unroll
    for (int rep = 0; rep < 8; ++rep) {
        int u = tid + rep * 256;
        int r = u >> 5;
        int d0 = (u & 31) * 4;
        float4 qv = *(const float4*)(Qg + (size_t)r * gstride + d0);
        int e = d0 ^ ((r & 7) << 3);
        short4v pk = {(short)bf16u(qv.x), (short)bf16u(qv.y), (short)bf16u(qv.z), (short)bf16u(qv.w)};
        *(short4v*)(QPs + r * 128 + e) = pk;
    }
    __syncthreads();

    // ---- preload Q fragments (A operand: row=ln, k-chunk=lq*8) ----
    short8v qfrag[4];
    {
        int rq = wave * 16 + ln;
#pragma unroll
        for (int ks = 0; ks < 4; ++ks) {
            int e = (ks * 32 + lq * 8) ^ ((rq & 7) << 3);
            qfrag[ks] = *(const short8v*)(QPs + rq * 128 + e);
        }
    }

    floatx4 accO[8];
#pragma unroll
    for (int dt = 0; dt < 8; ++dt) accO[dt] = (floatx4){0.f, 0.f, 0.f, 0.f};
    float mrow[4] = {-3.0e38f, -3.0e38f, -3.0e38f, -3.0e38f};
    float lrow[4] = {0.f, 0.f, 0.f, 0.f};

    const int nT = (slen + 63) >> 6;
    for (int t = 0; t < nT; ++t) {
        const int j0g = t * 64;
        __syncthreads();   // everyone done reading Ks/Vt of prev tile

        // ---- stage K tile [64][128] bf16 swizzled ----
        const float* Kg = K + ((size_t)(b * SS + j0g) * NHH + h) * HDD;
#pragma unroll
        for (int rep = 0; rep < 8; ++rep) {
            int u = tid + rep * 256;
            int r = u >> 5;
            int d0 = (u & 31) * 4;
            float4 kv = *(const float4*)(Kg + (size_t)r * gstride + d0);
            int e = d0 ^ ((r & 7) << 3);
            short4v pk = {(short)bf16u(kv.x), (short)bf16u(kv.y), (short)bf16u(kv.z), (short)bf16u(kv.w)};
            *(short4v*)(Ks + r * 128 + e) = pk;
        }
        // ---- stage V^T tile [128][64] bf16 swizzled (pair writes, conflict-free) ----
        const float* Vg = V + ((size_t)(b * SS + j0g) * NHH + h) * HDD;
#pragma unroll
        for (int rep = 0; rep < 4; ++rep) {
            int u = tid + rep * 256;
            int jp = u & 31;
            int j0 = jp * 2;
            int d0 = (u >> 5) * 4;
            const float* p0 = Vg + (size_t)j0 * gstride + d0;
            float4 va = *(const float4*)p0;
            float4 vb = *(const float4*)(p0 + gstride);
            float av[4] = {va.x, va.y, va.z, va.w};
            float bv[4] = {vb.x, vb.y, vb.z, vb.w};
#pragma unroll
            for (int i = 0; i < 4; ++i) {
                int d = d0 + i;
                int e = j0 ^ ((d & 7) << 3);
                unsigned pk = (unsigned)bf16u(av[i]) | ((unsigned)bf16u(bv[i]) << 16);
                *(unsigned*)(Vt + d * 64 + e) = pk;
            }
        }
        __syncthreads();

        // ---- QK^T: 4 col-tiles x 4 k-steps ----
        floatx4 acc_s[4];
#pragma unroll
        for (int nt = 0; nt < 4; ++nt) {
            acc_s[nt] = (floatx4){0.f, 0.f, 0.f, 0.f};
            int rk = nt * 16 + ln;
#pragma unroll
            for (int ks = 0; ks < 4; ++ks) {
                int e = (ks * 32 + lq * 8) ^ ((rk & 7) << 3);
                short8v kf = *(const short8v*)(Ks + rk * 128 + e);
                acc_s[nt] = __builtin_amdgcn_mfma_f32_16x16x32_bf16(qfrag[ks], kf, acc_s[nt], 0, 0, 0);
            }
        }

        // ---- online softmax (all lanes; rows = lq*4 + r) ----
        float s[4][4];
#pragma unroll
        for (int nt = 0; nt < 4; ++nt) {
            int j = j0g + nt * 16 + ln;
            bool valid = (j < slen);
#pragma unroll
            for (int r = 0; r < 4; ++r)
                s[nt][r] = valid ? acc_s[nt][r] * scale : -3.0e38f;
        }
        float fct[4], linv_dummy;
        (void)linv_dummy;
#pragma unroll
        for (int r = 0; r < 4; ++r) {
            float m4 = fmaxf(fmaxf(s[0][r], s[1][r]), fmaxf(s[2][r], s[3][r]));
            m4 = fmaxf(m4, __shfl_xor(m4, 1, 64));
            m4 = fmaxf(m4, __shfl_xor(m4, 2, 64));
            m4 = fmaxf(m4, __shfl_xor(m4, 4, 64));
            m4 = fmaxf(m4, __shfl_xor(m4, 8, 64));
            float mn = fmaxf(mrow[r], m4);
            fct[r] = __expf(mrow[r] - mn);
            mrow[r] = mn;
            float ls = 0.f;
#pragma unroll
            for (int nt = 0; nt < 4; ++nt) {
                float p = __expf(s[nt][r] - mn);
                s[nt][r] = p;
                ls += p;
            }
            ls += __shfl_xor(ls, 1, 64);
            ls += __shfl_xor(ls, 2, 64);
            ls += __shfl_xor(ls, 4, 64);
            ls += __shfl_xor(ls, 8, 64);
            lrow[r] = lrow[r] * fct[r] + ls;
        }

        // ---- write P (bf16) into this wave's private region of QPs ----
#pragma unroll
        for (int nt = 0; nt < 4; ++nt) {
#pragma unroll
            for (int r = 0; r < 4; ++r) {
                int rw = lq * 4 + r;                 // row within wave region
                int j = nt * 16 + ln;
                int e = j ^ ((rw & 7) << 3);
                QPs[(wave * 16 + rw) * 128 + e] = bf16u(s[nt][r]);
            }
        }

        // ---- rescale O ----
#pragma unroll
        for (int dt = 0; dt < 8; ++dt)
#pragma unroll
            for (int r = 0; r < 4; ++r) accO[dt][r] *= fct[r];

        // ---- PV: A=P (row=ln), B=V^T (col=d) ----
        short8v pfrag[2];
#pragma unroll
        for (int js = 0; js < 2; ++js) {
            int e = (js * 32 + lq * 8) ^ ((ln & 7) << 3);
            pfrag[js] = *(const short8v*)(QPs + (wave * 16 + ln) * 128 + e);
        }
#pragma unroll
        for (int dt = 0; dt < 8; ++dt) {
            int d = dt * 16 + ln;
#pragma unroll
            for (int js = 0; js < 2; ++js) {
                int e = (js * 32 + lq * 8) ^ ((d & 7) << 3);
                short8v vf = *(const short8v*)(Vt + d * 64 + e);
                accO[dt] = __builtin_amdgcn_mfma_f32_16x16x32_bf16(pfrag[js], vf, accO[dt], 0, 0, 0);
            }
        }
    }

    // ---- finalize: divide by l, write O over Q (fp32) ----
    float linv[4];
#pragma unroll
    for (int r = 0; r < 4; ++r) linv[r] = 1.0f / lrow[r];
    float* Og = Q + ((size_t)(b * SS + i0) * NHH + h) * HDD;
#pragma unroll
    for (int dt = 0; dt < 8; ++dt) {
#pragma unroll
        for (int r = 0; r < 4; ++r) {
            int qr = wave * 16 + lq * 4 + r;
            int d = dt * 16 + ln;
            Og[(size_t)qr * gstride + d] = accO[dt][r] * linv[r];
        }
    }
}

extern "C" void kernel_launch(void* const* d_in, const int* in_sizes, int n_in,
                              void* d_out, int out_size, void* d_ws, size_t ws_size,
                              hipStream_t stream)
{
    const float* x     = (const float*)d_in[0];
    const int*   seq   = (const int*)d_in[1];
    const float* freqs = (const float*)d_in[3];
    const float* Wq    = (const float*)d_in[4];
    const float* bq    = (const float*)d_in[5];
    const float* Wk    = (const float*)d_in[6];
    const float* bk    = (const float*)d_in[7];
    const float* Wv    = (const float*)d_in[8];
    const float* bv    = (const float*)d_in[9];
    const float* Wo    = (const float*)d_in[10];
    const float* bo    = (const float*)d_in[11];
    const float* gq    = (const float*)d_in[12];
    const float* gk    = (const float*)d_in[13];

    float* out = (float*)d_out;
    float* ws  = (float*)d_ws;
    const size_t MD = (size_t)MM * DIMM;

    float* q = ws;            // q -> attn output (in-place)
    float* k = ws + MD;
    float* v = out;           // v in d_out; final GEMM overwrites after last use

    const int ngrid = (MM / 128) * (DIMM / 128);   // 384
    gemm_xt_bias_mfma<<<ngrid, 256, 0, stream>>>(x, Wq, bq, q);
    gemm_xt_bias_mfma<<<ngrid, 256, 0, stream>>>(x, Wk, bk, k);
    gemm_xt_bias_mfma<<<ngrid, 256, 0, stream>>>(x, Wv, bv, v);
    rmsnorm_rope<<<dim3(MM, 2), 256, 0, stream>>>(q, k, gq, gk, freqs);
    flash_attn_mfma<<<dim3(SS / 64, NHH, BB), 256, 0, stream>>>(q, k, v, seq);
    gemm_xt_bias_mfma<<<ngrid, 256, 0, stream>>>(q, Wo, bo, out);
}

// Round 4
// 386.695 us; speedup vs baseline: 6.9088x; 2.3127x over previous
//
#include <hip/hip_runtime.h>
#include <cmath>

#define BB   2
#define SS   1024
#define DIMM 3072
#define NHH  24
#define HDD  128
#define MM   (BB * SS)

typedef _Float16 f16;
typedef __attribute__((ext_vector_type(8))) _Float16 half8;
typedef __attribute__((ext_vector_type(4))) float floatx4;
typedef unsigned int u32;
typedef const __attribute__((address_space(1))) u32* gp1;
typedef __attribute__((address_space(3))) u32* lp3;

__device__ __forceinline__ void gload_lds16(const void* g, void* l) {
    __builtin_amdgcn_global_load_lds((gp1)g, (lp3)l, 16, 0, 0);
}

// ---------------- fp32 -> fp16 converter ----------------
__global__ __launch_bounds__(256) void cvt_f16_kernel(
    const float* __restrict__ in, f16* __restrict__ outp, int n8)
{
    int i = blockIdx.x * 256 + threadIdx.x;
    if (i >= n8) return;
    const float4* p = (const float4*)(in + (size_t)i * 8);
    float4 a = p[0], b = p[1];
    half8 h = {(f16)a.x, (f16)a.y, (f16)a.z, (f16)a.w,
               (f16)b.x, (f16)b.y, (f16)b.z, (f16)b.w};
    *(half8*)(outp + (size_t)i * 8) = h;
}

// ---------------- GEMM: C = A16 @ W^T + bias (f16 MFMA, fp32 accum) ----------------
// A16: (2048, 3072) f16 row-major. W: (N, 3072) f32 row-major (reg-staged+cvt).
// QKV=true: N spans 9216 (Wq|Wk|Wv), f16 outputs to D0/D1/D2. else f32 output F.
template<bool QKV>
__global__ __launch_bounds__(256) void gemm_f16(
    const f16* __restrict__ A,
    const float* __restrict__ W0, const float* __restrict__ W1, const float* __restrict__ W2,
    const float* __restrict__ b0, const float* __restrict__ b1, const float* __restrict__ b2,
    f16* __restrict__ D0, f16* __restrict__ D1, f16* __restrict__ D2,
    float* __restrict__ F)
{
    constexpr int K = DIMM;
    constexpr int NSTEP = K / 32;
    __shared__ f16 As[128 * 32];
    __shared__ f16 Bs[128 * 32];

    const int tid  = threadIdx.x;
    const int lane = tid & 63;
    const int wave = tid >> 6;
    const int wm = wave >> 1, wn = wave & 1;
    const int lr = lane & 15;
    const int lq = lane >> 4;

    // bijective XCD swizzle (grid % 8 == 0 for both 1152 and 384)
    const int id  = blockIdx.x;
    const int cpx = (int)gridDim.x >> 3;
    const int swz = (id & 7) * cpx + (id >> 3);
    const int bm = (swz & 15) << 7;        // 16 M-tiles
    const int bn = (swz >> 4) << 7;

    const float* W; const float* bias; f16* D = nullptr;
    int nloc = bn;
    if constexpr (QKV) {
        int sel = bn / DIMM;
        nloc = bn - sel * DIMM;
        W    = sel == 0 ? W0 : (sel == 1 ? W1 : W2);
        bias = sel == 0 ? b0 : (sel == 1 ? b1 : b2);
        D    = sel == 0 ? D0 : (sel == 1 ? D1 : D2);
    } else { W = W0; bias = b0; }

    // B staging coords: rows r0, r0+64; cols c8..c8+7
    const int r0 = tid >> 2;
    const int c8 = (tid & 3) << 3;
    const float* bp0 = W + (size_t)(nloc + r0) * K + c8;
    const float* bp1 = W + (size_t)(nloc + r0 + 64) * K + c8;

    // A staging via global_load_lds: per-wave 2 issues of 16 rows
    const int arow_l = lane >> 2;
    const int acol_l = (lane & 3) << 3;
    const f16* agbase = A + (size_t)bm * K;

    float4 sb00, sb01, sb10, sb11;
    auto LOADB = [&](int k0) {
        sb00 = *(const float4*)(bp0 + k0); sb01 = *(const float4*)(bp0 + k0 + 4);
        sb10 = *(const float4*)(bp1 + k0); sb11 = *(const float4*)(bp1 + k0 + 4);
    };
    auto STOREB = [&]() {
        half8 h0 = {(f16)sb00.x, (f16)sb00.y, (f16)sb00.z, (f16)sb00.w,
                    (f16)sb01.x, (f16)sb01.y, (f16)sb01.z, (f16)sb01.w};
        half8 h1 = {(f16)sb10.x, (f16)sb10.y, (f16)sb10.z, (f16)sb10.w,
                    (f16)sb11.x, (f16)sb11.y, (f16)sb11.z, (f16)sb11.w};
        *(half8*)&Bs[r0 * 32 + c8]        = h0;
        *(half8*)&Bs[(r0 + 64) * 32 + c8] = h1;
    };

    floatx4 acc[4][4];
#pragma unroll
    for (int i = 0; i < 4; ++i)
#pragma unroll
        for (int j = 0; j < 4; ++j) acc[i][j] = (floatx4){0.f, 0.f, 0.f, 0.f};

    LOADB(0);
    for (int ks = 0; ks < NSTEP; ++ks) {
        const int k0 = ks * 32;
        __syncthreads();                    // consumers done with LDS
#pragma unroll
        for (int i = 0; i < 2; ++i) {       // async A: global f16 -> LDS
            int rbase = wave * 32 + i * 16;
            gload_lds16(agbase + (size_t)(rbase + arow_l) * K + k0 + acol_l,
                        &As[rbase * 32]);
        }
        STOREB();
        __syncthreads();                    // tiles ready (vmcnt drain at barrier)
        if (ks + 1 < NSTEP) LOADB(k0 + 32); // prefetch flies under MFMA

        half8 af[4], bf[4];
#pragma unroll
        for (int i = 0; i < 4; ++i) {
            af[i] = *(const half8*)&As[(wm * 64 + i * 16 + lr) * 32 + lq * 8];
            bf[i] = *(const half8*)&Bs[(wn * 64 + i * 16 + lr) * 32 + lq * 8];
        }
#pragma unroll
        for (int mi = 0; mi < 4; ++mi)
#pragma unroll
            for (int ni = 0; ni < 4; ++ni)
                acc[mi][ni] = __builtin_amdgcn_mfma_f32_16x16x32_f16(af[mi], bf[ni], acc[mi][ni], 0, 0, 0);
    }

    // epilogue: C/D layout col = lane&15, row = (lane>>4)*4 + reg
    const int crow0 = bm + wm * 64 + (lq << 2);
    const int ccol0 = nloc + wn * 64;
#pragma unroll
    for (int ni = 0; ni < 4; ++ni) {
        const int col = ccol0 + ni * 16 + lr;
        const float bv = bias[col];
#pragma unroll
        for (int mi = 0; mi < 4; ++mi) {
            const int row = crow0 + mi * 16;
#pragma unroll
            for (int r2 = 0; r2 < 4; ++r2) {
                if constexpr (QKV)
                    D[(size_t)(row + r2) * DIMM + col] = (f16)(acc[mi][ni][r2] + bv);
                else
                    F[(size_t)(row + r2) * DIMM + col] = acc[mi][ni][r2] + bv;
            }
        }
    }
}

// ---------------- RMSNorm (over 3072) + RoPE, f16 in/out ----------------
__global__ __launch_bounds__(192) void rmsnorm_rope_f16(
    f16* __restrict__ q, f16* __restrict__ k,
    const float* __restrict__ gq, const float* __restrict__ gk,
    const float* __restrict__ freqs)
{
    f16* t = (blockIdx.y == 0) ? q : k;
    const float* g = (blockIdx.y == 0) ? gq : gk;
    const int row = blockIdx.x;
    const int s = row & (SS - 1);
    const int tid = threadIdx.x;
    f16* base = t + (size_t)row * DIMM + tid * 16;

    half8 v0 = *(const half8*)base;
    half8 v1 = *(const half8*)(base + 8);
    float v[16];
#pragma unroll
    for (int j = 0; j < 8; ++j) { v[j] = (float)v0[j]; v[8 + j] = (float)v1[j]; }

    float ssq = 0.f;
#pragma unroll
    for (int j = 0; j < 16; ++j) ssq += v[j] * v[j];
#pragma unroll
    for (int off = 32; off > 0; off >>= 1) ssq += __shfl_down(ssq, off, 64);
    __shared__ float red[3];
    if ((tid & 63) == 0) red[tid >> 6] = ssq;
    __syncthreads();
    float tot = red[0] + red[1] + red[2];
    float sc = rsqrtf(tot * (1.0f / (float)DIMM) + 1e-6f);

    const float* gp = g + tid * 16;
    float y[16];
#pragma unroll
    for (int j = 0; j < 16; ++j) y[j] = v[j] * sc * gp[j];

#pragma unroll
    for (int p = 0; p < 8; ++p) {
        int idx = tid * 16 + 2 * p;
        int f = (idx & 127) >> 1;
        float ang = freqs[s * 64 + f];
        float cc = cosf(ang), sn = sinf(ang);
        float e = y[2 * p], o = y[2 * p + 1];
        y[2 * p]     = e * cc - o * sn;
        y[2 * p + 1] = e * sn + o * cc;
    }
    half8 o0, o1;
#pragma unroll
    for (int j = 0; j < 8; ++j) { o0[j] = (f16)y[j]; o1[j] = (f16)y[8 + j]; }
    *(half8*)base       = o0;
    *(half8*)(base + 8) = o1;
}

// ---------------- Flash attention: f16 MFMA, wave-parallel online softmax ----------------
__global__ __launch_bounds__(256) void flash_attn_f16(
    const f16* __restrict__ Q, const f16* __restrict__ K,
    const f16* __restrict__ V, const int* __restrict__ seq_lens,
    f16* __restrict__ O)
{
    __shared__ f16 QPs[64 * 128];   // Q tile; wave regions reused as P buffer
    __shared__ f16 Ks[64 * 128];
    __shared__ f16 Vt[128 * 64];    // V transposed [d][j], swizzled

    const int tid  = threadIdx.x;
    const int lane = tid & 63;
    const int wave = tid >> 6;
    const int ln = lane & 15;
    const int lq = lane >> 4;
    const int i0 = blockIdx.x * 64;
    const int h  = blockIdx.y;
    const int b  = blockIdx.z;
    const int slen = seq_lens[b];
    const float scale = 0.08838834764831845f;
    const size_t gstride = NHH * HDD;

    const f16* Qg = Q + ((size_t)(b * SS + i0) * NHH + h) * HDD;
#pragma unroll
    for (int rep = 0; rep < 4; ++rep) {
        int u = tid + rep * 256;
        int r = u >> 4, d0 = (u & 15) << 3;
        half8 qv = *(const half8*)(Qg + (size_t)r * gstride + d0);
        *(half8*)(QPs + r * 128 + (d0 ^ ((r & 7) << 3))) = qv;
    }
    __syncthreads();

    half8 qfrag[4];
    {
        int rq = wave * 16 + ln;
#pragma unroll
        for (int ks = 0; ks < 4; ++ks)
            qfrag[ks] = *(const half8*)(QPs + rq * 128 + ((ks * 32 + lq * 8) ^ ((rq & 7) << 3)));
    }

    floatx4 accO[8];
#pragma unroll
    for (int dt = 0; dt < 8; ++dt) accO[dt] = (floatx4){0.f, 0.f, 0.f, 0.f};
    float mrow[4] = {-3.0e38f, -3.0e38f, -3.0e38f, -3.0e38f};
    float lrow[4] = {0.f, 0.f, 0.f, 0.f};

    const int nT = (slen + 63) >> 6;
    for (int t = 0; t < nT; ++t) {
        const int j0g = t * 64;
        __syncthreads();

        const f16* Kg = K + ((size_t)(b * SS + j0g) * NHH + h) * HDD;
#pragma unroll
        for (int rep = 0; rep < 4; ++rep) {
            int u = tid + rep * 256;
            int r = u >> 4, d0 = (u & 15) << 3;
            half8 kv = *(const half8*)(Kg + (size_t)r * gstride + d0);
            *(half8*)(Ks + r * 128 + (d0 ^ ((r & 7) << 3))) = kv;
        }
        const f16* Vg = V + ((size_t)(b * SS + j0g) * NHH + h) * HDD;
#pragma unroll
        for (int rep = 0; rep < 2; ++rep) {
            int u = tid + rep * 256;
            int jp = u & 31, j0 = jp * 2;
            int d0 = (u >> 5) << 3;
            half8 va = *(const half8*)(Vg + (size_t)j0 * gstride + d0);
            half8 vb = *(const half8*)(Vg + (size_t)(j0 + 1) * gstride + d0);
#pragma unroll
            for (int i = 0; i < 8; ++i) {
                int d = d0 + i;
                union { f16 h[2]; u32 w; } pk;
                pk.h[0] = va[i]; pk.h[1] = vb[i];
                *(u32*)(Vt + d * 64 + (j0 ^ ((d & 7) << 3))) = pk.w;
            }
        }
        __syncthreads();

        // QK^T
        floatx4 acc_s[4];
#pragma unroll
        for (int nt = 0; nt < 4; ++nt) {
            acc_s[nt] = (floatx4){0.f, 0.f, 0.f, 0.f};
            int rk = nt * 16 + ln;
#pragma unroll
            for (int ks = 0; ks < 4; ++ks) {
                half8 kf = *(const half8*)(Ks + rk * 128 + ((ks * 32 + lq * 8) ^ ((rk & 7) << 3)));
                acc_s[nt] = __builtin_amdgcn_mfma_f32_16x16x32_f16(qfrag[ks], kf, acc_s[nt], 0, 0, 0);
            }
        }

        // online softmax (rows = lq*4 + r of this wave's 16)
        float s[4][4];
#pragma unroll
        for (int nt = 0; nt < 4; ++nt) {
            int j = j0g + nt * 16 + ln;
            bool valid = (j < slen);
#pragma unroll
            for (int r = 0; r < 4; ++r)
                s[nt][r] = valid ? acc_s[nt][r] * scale : -3.0e38f;
        }
        float fct[4];
#pragma unroll
        for (int r = 0; r < 4; ++r) {
            float m4 = fmaxf(fmaxf(s[0][r], s[1][r]), fmaxf(s[2][r], s[3][r]));
            m4 = fmaxf(m4, __shfl_xor(m4, 1, 64));
            m4 = fmaxf(m4, __shfl_xor(m4, 2, 64));
            m4 = fmaxf(m4, __shfl_xor(m4, 4, 64));
            m4 = fmaxf(m4, __shfl_xor(m4, 8, 64));
            float mn = fmaxf(mrow[r], m4);
            fct[r] = __expf(mrow[r] - mn);
            mrow[r] = mn;
            float ls = 0.f;
#pragma unroll
            for (int nt = 0; nt < 4; ++nt) {
                float p = __expf(s[nt][r] - mn);
                s[nt][r] = p;
                ls += p;
            }
            ls += __shfl_xor(ls, 1, 64);
            ls += __shfl_xor(ls, 2, 64);
            ls += __shfl_xor(ls, 4, 64);
            ls += __shfl_xor(ls, 8, 64);
            lrow[r] = lrow[r] * fct[r] + ls;
        }

        // write P (f16) into this wave's private region of QPs
#pragma unroll
        for (int nt = 0; nt < 4; ++nt) {
#pragma unroll
            for (int r = 0; r < 4; ++r) {
                int rw = lq * 4 + r;
                int j = nt * 16 + ln;
                QPs[(wave * 16 + rw) * 128 + (j ^ ((rw & 7) << 3))] = (f16)s[nt][r];
            }
        }

        // rescale O
#pragma unroll
        for (int dt = 0; dt < 8; ++dt)
#pragma unroll
            for (int r = 0; r < 4; ++r) accO[dt][r] *= fct[r];

        // PV
        half8 pfrag[2];
#pragma unroll
        for (int js = 0; js < 2; ++js)
            pfrag[js] = *(const half8*)(QPs + (wave * 16 + ln) * 128 + ((js * 32 + lq * 8) ^ ((ln & 7) << 3)));
#pragma unroll
        for (int dt = 0; dt < 8; ++dt) {
            int d = dt * 16 + ln;
#pragma unroll
            for (int js = 0; js < 2; ++js) {
                half8 vf = *(const half8*)(Vt + d * 64 + ((js * 32 + lq * 8) ^ ((d & 7) << 3)));
                accO[dt] = __builtin_amdgcn_mfma_f32_16x16x32_f16(pfrag[js], vf, accO[dt], 0, 0, 0);
            }
        }
    }

    // finalize: /l, write O (f16)
    float linv[4];
#pragma unroll
    for (int r = 0; r < 4; ++r) linv[r] = 1.0f / lrow[r];
    f16* Og = O + ((size_t)(b * SS + i0) * NHH + h) * HDD;
#pragma unroll
    for (int dt = 0; dt < 8; ++dt) {
#pragma unroll
        for (int r = 0; r < 4; ++r) {
            int qr = wave * 16 + lq * 4 + r;
            int d = dt * 16 + ln;
            Og[(size_t)qr * gstride + d] = (f16)(accO[dt][r] * linv[r]);
        }
    }
}

extern "C" void kernel_launch(void* const* d_in, const int* in_sizes, int n_in,
                              void* d_out, int out_size, void* d_ws, size_t ws_size,
                              hipStream_t stream)
{
    const float* x     = (const float*)d_in[0];
    const int*   seq   = (const int*)d_in[1];
    const float* freqs = (const float*)d_in[3];
    const float* Wq    = (const float*)d_in[4];
    const float* bq    = (const float*)d_in[5];
    const float* Wk    = (const float*)d_in[6];
    const float* bk    = (const float*)d_in[7];
    const float* Wv    = (const float*)d_in[8];
    const float* bv    = (const float*)d_in[9];
    const float* Wo    = (const float*)d_in[10];
    const float* bo    = (const float*)d_in[11];
    const float* gq    = (const float*)d_in[12];
    const float* gk    = (const float*)d_in[13];

    float* out = (float*)d_out;
    const size_t MD = (size_t)MM * DIMM;

    f16* X16 = (f16*)d_ws;          // later reused as O16
    f16* q16 = X16 + MD;
    f16* k16 = X16 + 2 * MD;
    f16* v16 = (f16*)d_out;         // lives in d_out; final GEMM overwrites after last use

    cvt_f16_kernel<<<(int)(MD / (256 * 8)), 256, 0, stream>>>(x, X16, (int)(MD / 8));
    gemm_f16<true><<<(MM / 128) * (3 * DIMM / 128), 256, 0, stream>>>(
        X16, Wq, Wk, Wv, bq, bk, bv, q16, k16, v16, nullptr);
    rmsnorm_rope_f16<<<dim3(MM, 2), 192, 0, stream>>>(q16, k16, gq, gk, freqs);
    flash_attn_f16<<<dim3(SS / 64, NHH, BB), 256, 0, stream>>>(q16, k16, v16, seq, X16);
    gemm_f16<false><<<(MM / 128) * (DIMM / 128), 256, 0, stream>>>(
        X16, Wo, nullptr, nullptr, bo, nullptr, nullptr, nullptr, nullptr, nullptr, out);
}